// Round 3
// baseline (174.213 us; speedup 1.0000x reference)
//
#include <hip/hip_runtime.h>
#include <hip/hip_bf16.h>

#define NRES 256
#define DPAIR 128
#define NHEADS 16
#define DHEAD 32
#define DINNER 512

typedef unsigned short u16;
typedef __attribute__((ext_vector_type(4))) float f32x4;
typedef __attribute__((ext_vector_type(8))) short s16x8;
typedef __attribute__((ext_vector_type(4))) short s16x4;

// (1/sqrt(32)) * log2(e): folded into q so softmax can use exp2 directly.
#define QSCALE (0.17677669529663687f * 1.4426950408889634f)

__device__ __forceinline__ u16 f32_to_bf16(float f) {
    unsigned int u = __builtin_bit_cast(unsigned int, f);
    unsigned int r = (u + 0x7FFFu + ((u >> 16) & 1u)) >> 16;
    return (u16)r;
}

__device__ __forceinline__ float fast_exp2(float x) {
#if __has_builtin(__builtin_amdgcn_exp2f)
    return __builtin_amdgcn_exp2f(x);
#else
    return exp2f(x);
#endif
}

__device__ __forceinline__ f32x4 mfma_16x16x16_bf16(s16x4 a, s16x4 b, f32x4 c) {
#if __has_builtin(__builtin_amdgcn_mfma_f32_16x16x16bf16_1k)
    return __builtin_amdgcn_mfma_f32_16x16x16bf16_1k(a, b, c, 0, 0, 0);
#elif __has_builtin(__builtin_amdgcn_mfma_f32_16x16x16_bf16)
    return __builtin_amdgcn_mfma_f32_16x16x16_bf16(a, b, c, 0, 0, 0);
#else
    f32x4 d;
    asm volatile("v_mfma_f32_16x16x16_bf16 %0, %1, %2, %3"
                 : "=v"(d) : "v"(a), "v"(b), "v"(c));
    return d;
#endif
}

// async global->LDS, 16B per lane. Dest is wave-uniform base + lane*16 (linear).
__device__ __forceinline__ void gll16(const void* g, void* l) {
    __builtin_amdgcn_global_load_lds(
        (__attribute__((address_space(1))) unsigned int*)(uintptr_t)g,
        (__attribute__((address_space(3))) unsigned int*)(unsigned int)(uintptr_t)l,
        16, 0, 0);
}

// ---------------- prep: pair f32 -> bf16 (only when ws allows) ----------------
__global__ __launch_bounds__(256) void prep_pair(const float* __restrict__ pair,
                                                 u16* __restrict__ pairb) {
    const int id = blockIdx.x * 256 + threadIdx.x;   // 1048576 ids x 8 elems
    const float4* s = reinterpret_cast<const float4*>(pair) + (size_t)id * 2;
    const float4 v0 = s[0], v1 = s[1];
    ushort4 lo, hi;
    lo.x = f32_to_bf16(v0.x); lo.y = f32_to_bf16(v0.y);
    lo.z = f32_to_bf16(v0.z); lo.w = f32_to_bf16(v0.w);
    hi.x = f32_to_bf16(v1.x); hi.y = f32_to_bf16(v1.y);
    hi.z = f32_to_bf16(v1.z); hi.w = f32_to_bf16(v1.w);
    ushort4* d = reinterpret_cast<ushort4*>(pairb + (size_t)id * 8);
    d[0] = lo; d[1] = hi;
}

// ---------------- weight convert + transpose to bf16 ----------------
__global__ __launch_bounds__(256) void wconv(const float* __restrict__ Wq,
                                             const float* __restrict__ Wk,
                                             const float* __restrict__ Wv,
                                             const float* __restrict__ Wo,
                                             u16* wq_t, u16* wk_t, u16* wv_t, u16* wo_t) {
    int id = blockIdx.x * 256 + threadIdx.x;
    if (id < 3 * 65536) {
        int m = id / 65536;
        int e = id % 65536;
        int k = e >> 9, n = e & 511;
        const float* W = (m == 0) ? Wq : ((m == 1) ? Wk : Wv);
        u16* Wt = (m == 0) ? wq_t : ((m == 1) ? wk_t : wv_t);
        Wt[n * 128 + k] = f32_to_bf16(W[e]);
    } else {
        int e = id - 3 * 65536;
        int k = e >> 7, n = e & 127;
        wo_t[n * 512 + k] = f32_to_bf16(Wo[e]);
    }
}

// ---------------- Kernel 1: QKV projection GEMM ----------------
// grid 6144 = 512 row-tiles x 12 col-tiles (128x128 each, K=128). One barrier.
// Dispatch decode keeps all 12 col-tiles of a row-tile on one XCD.
// q,k: swapped MFMA operands -> lane holds 4 consecutive cols (ushort4 stores).
// v: unswapped -> lane holds 4 consecutive rows j (ushort4 stores into vT).
template <bool PB>
__global__ __launch_bounds__(256) void qkv_proj(const float* __restrict__ pair_f32,
                                                const u16* __restrict__ pairb,
                                                const u16* __restrict__ wq_t,
                                                const u16* __restrict__ wk_t,
                                                const u16* __restrict__ wv_t,
                                                const float* __restrict__ bq,
                                                const float* __restrict__ bk,
                                                const float* __restrict__ bv,
                                                u16* __restrict__ q_ws,
                                                u16* __restrict__ k_ws,
                                                u16* __restrict__ vT_ws) {
    __shared__ u16 As[128 * 128];
    __shared__ u16 Bs[128 * 128];
    const int tid = threadIdx.x;
    const int wave = tid >> 6, lane = tid & 63;
    const int g = lane >> 4, l15 = lane & 15;

    // decode: XCD = d&7 pinned to row-tile group; col-tiles cycle fastest per XCD
    const int d = blockIdx.x;
    const int qd = d >> 3;
    const int c = qd % 12;
    const int r = (d & 7) + 8 * (qd / 12);
    const int m0 = r * 128;
    const int mat = c >> 2, ncol0 = (c & 3) * 128;
    const u16* Wt = (mat == 0) ? wq_t : ((mat == 1) ? wk_t : wv_t);
    const float* bias = (mat == 0) ? bq : ((mat == 1) ? bk : bv);

    // ---- stage B: 32 KiB contiguous, source-swizzled (chunk ^= row&7) ----
    {
        const char* wb = (const char*)(Wt + (size_t)ncol0 * 128);
        for (int it = 0; it < 8; ++it) {
            const int chunk = wave * 8 + it;
            const int row = chunk * 4 + (lane >> 4);
            const int col = (lane & 15) ^ (row & 7);
            gll16(wb + row * 256 + col * 16, (void*)(Bs + chunk * 512));
        }
    }
    // ---- stage A ----
    if constexpr (PB) {
        const char* ab = (const char*)(pairb + (size_t)m0 * 128);
        for (int it = 0; it < 8; ++it) {
            const int chunk = wave * 8 + it;
            const int row = chunk * 4 + (lane >> 4);
            const int col = (lane & 15) ^ (row & 7);
            gll16(ab + row * 256 + col * 16, (void*)(As + chunk * 512));
        }
    } else {
        // fallback: reg-stage from f32 with swizzled ds_write
        for (int it = 0; it < 16; ++it) {
            const int L = tid + it * 256;
            const int row = L >> 5, c4 = L & 31;       // c4 = 4-elem (8B) group
            const float4 v = *(reinterpret_cast<const float4*>(pair_f32 + (size_t)(m0 + row) * 128) + c4);
            ushort4 pk;
            pk.x = f32_to_bf16(v.x); pk.y = f32_to_bf16(v.y);
            pk.z = f32_to_bf16(v.z); pk.w = f32_to_bf16(v.w);
            const int chunk = c4 >> 1, half = c4 & 1;
            const int sc = chunk ^ (row & 7);
            *reinterpret_cast<ushort4*>(&As[row * 128 + sc * 8 + half * 4]) = pk;
        }
    }
    __syncthreads();

    f32x4 acc[2][8];
    for (int rf = 0; rf < 2; ++rf)
        for (int cf = 0; cf < 8; ++cf) acc[rf][cf] = f32x4{0.f, 0.f, 0.f, 0.f};

    for (int kk = 0; kk < 4; ++kk) {
        s16x8 a[2], b[8];
        for (int rf = 0; rf < 2; ++rf) {
            const int row = wave * 32 + rf * 16 + l15;
            const int ch = (kk * 4 + g) ^ (row & 7);
            a[rf] = *reinterpret_cast<s16x8*>(&As[row * 128 + ch * 8]);
        }
        for (int cf = 0; cf < 8; ++cf) {
            const int n = cf * 16 + l15;
            const int ch = (kk * 4 + g) ^ (n & 7);
            b[cf] = *reinterpret_cast<s16x8*>(&Bs[n * 128 + ch * 8]);
        }
        if (mat < 2) {
            for (int rf = 0; rf < 2; ++rf)
                for (int cf = 0; cf < 8; ++cf)
                    acc[rf][cf] = __builtin_amdgcn_mfma_f32_16x16x32_bf16(b[cf], a[rf], acc[rf][cf], 0, 0, 0);
        } else {
            for (int rf = 0; rf < 2; ++rf)
                for (int cf = 0; cf < 8; ++cf)
                    acc[rf][cf] = __builtin_amdgcn_mfma_f32_16x16x32_bf16(a[rf], b[cf], acc[rf][cf], 0, 0, 0);
        }
    }

    if (mat < 2) {
        // lane: row = ...+l15, cols = ncol0+cf*16+g*4+(0..3)
        const float sc = (mat == 0) ? QSCALE : 1.0f;
        u16* dst = (mat == 0) ? q_ws : k_ws;
        for (int rf = 0; rf < 2; ++rf) {
            const size_t row = m0 + wave * 32 + rf * 16 + l15;
            for (int cf = 0; cf < 8; ++cf) {
                const int col = ncol0 + cf * 16 + g * 4;
                const float4 bv4 = *reinterpret_cast<const float4*>(bias + col);
                ushort4 o;
                o.x = f32_to_bf16((acc[rf][cf][0] + bv4.x) * sc);
                o.y = f32_to_bf16((acc[rf][cf][1] + bv4.y) * sc);
                o.z = f32_to_bf16((acc[rf][cf][2] + bv4.z) * sc);
                o.w = f32_to_bf16((acc[rf][cf][3] + bv4.w) * sc);
                *reinterpret_cast<ushort4*>(dst + row * 512 + col) = o;
            }
        }
    } else {
        // lane: rows j = ...+g*4+(0..3) consecutive, col = ncol0+cf*16+l15
        for (int rf = 0; rf < 2; ++rf) {
            const int rowb = m0 + wave * 32 + rf * 16 + g * 4;
            const int i_ = rowb >> 8, j_ = rowb & 255;
            for (int cf = 0; cf < 8; ++cf) {
                const int col = ncol0 + cf * 16 + l15;
                const float bv = bias[col];
                ushort4 o;
                o.x = f32_to_bf16(acc[rf][cf][0] + bv);
                o.y = f32_to_bf16(acc[rf][cf][1] + bv);
                o.z = f32_to_bf16(acc[rf][cf][2] + bv);
                o.w = f32_to_bf16(acc[rf][cf][3] + bv);
                *reinterpret_cast<ushort4*>(vT_ws + ((size_t)i_ * 512 + col) * 256 + j_) = o;
            }
        }
    }
}

// ---------------- Kernel 2: triangular attention per (i,h) (unchanged) ----------------
__global__ __launch_bounds__(256, 4) void attn(const u16* __restrict__ k_ws,
                                               const u16* __restrict__ vT_ws,
                                               u16* qo_ws) {
    __shared__ u16 Ks[256 * 40];    // 256 k-rows x 32 c, pitch 40
    __shared__ u16 Vt[32 * 264];    // 32 c x 256 keys, pitch 264

    const int bx = ((blockIdx.x & 7) << 9) | (blockIdx.x >> 3);
    const int i = bx >> 4, h = bx & 15;
    const int tid = threadIdx.x;
    const size_t base = ((size_t)i * 256) * 512 + h * 32;

    for (int it = 0; it < 4; ++it) {
        int L = tid + it * 256;
        int row = L >> 2, seg = L & 3;
        *reinterpret_cast<s16x8*>(&Ks[row * 40 + seg * 8]) =
            *reinterpret_cast<const s16x8*>(k_ws + base + (size_t)row * 512 + seg * 8);
    }
    const size_t vbase = ((size_t)i * 512 + h * 32) * 256;
    for (int it = 0; it < 4; ++it) {
        int L = tid + it * 256;
        int c = L >> 5, seg = L & 31;
        *reinterpret_cast<s16x8*>(&Vt[c * 264 + seg * 8]) =
            *reinterpret_cast<const s16x8*>(vT_ws + vbase + (size_t)c * 256 + seg * 8);
    }
    __syncthreads();

    const int wave = tid >> 6, lane = tid & 63;
    const int g = lane >> 4, l15 = lane & 15;

    for (int ch = 0; ch < 4; ++ch) {
        const int t = (ch == 0) ? wave : (ch == 1) ? (7 - wave) : (ch == 2) ? (8 + wave) : (15 - wave);
        const int jbase = t * 16;
        const int ktmax = t + 1;

        const s16x8 qf = *reinterpret_cast<const s16x8*>(
            qo_ws + base + (size_t)(jbase + l15) * 512 + g * 8);

        f32x4 o0 = {0.f, 0.f, 0.f, 0.f}, o1 = {0.f, 0.f, 0.f, 0.f};
        float sum = 0.f;

        for (int kt = 0; kt < ktmax; ++kt) {
            const s16x8 kf = *reinterpret_cast<s16x8*>(&Ks[(kt * 16 + l15) * 40 + g * 8]);
            f32x4 s = __builtin_amdgcn_mfma_f32_16x16x32_bf16(kf, qf, f32x4{0.f, 0.f, 0.f, 0.f}, 0, 0, 0);
            float p0, p1, p2, p3;
            if (kt == t) {
                p0 = ((g * 4 + 0) > l15) ? 0.f : fast_exp2(s[0]);
                p1 = ((g * 4 + 1) > l15) ? 0.f : fast_exp2(s[1]);
                p2 = ((g * 4 + 2) > l15) ? 0.f : fast_exp2(s[2]);
                p3 = ((g * 4 + 3) > l15) ? 0.f : fast_exp2(s[3]);
            } else {
                p0 = fast_exp2(s[0]); p1 = fast_exp2(s[1]);
                p2 = fast_exp2(s[2]); p3 = fast_exp2(s[3]);
            }
            sum += (p0 + p1) + (p2 + p3);
            unsigned e0 = __builtin_bit_cast(unsigned, p0) + 0x8000u;
            unsigned e1 = __builtin_bit_cast(unsigned, p1) + 0x8000u;
            unsigned e2 = __builtin_bit_cast(unsigned, p2) + 0x8000u;
            unsigned e3 = __builtin_bit_cast(unsigned, p3) + 0x8000u;
            uint2 pw;
            pw.x = __builtin_amdgcn_perm(e1, e0, 0x07060302u);
            pw.y = __builtin_amdgcn_perm(e3, e2, 0x07060302u);
            const s16x4 pb = __builtin_bit_cast(s16x4, pw);
            const s16x4 va0 = *reinterpret_cast<s16x4*>(&Vt[l15 * 264 + kt * 16 + g * 4]);
            const s16x4 va1 = *reinterpret_cast<s16x4*>(&Vt[(16 + l15) * 264 + kt * 16 + g * 4]);
            o0 = mfma_16x16x16_bf16(va0, pb, o0);
            o1 = mfma_16x16x16_bf16(va1, pb, o1);
        }

        sum += __shfl_xor(sum, 16, 64);
        sum += __shfl_xor(sum, 32, 64);
        const float rinv = 1.0f / sum;

        unsigned x0 = __builtin_bit_cast(unsigned, o0[0] * rinv) + 0x8000u;
        unsigned x1 = __builtin_bit_cast(unsigned, o0[1] * rinv) + 0x8000u;
        unsigned x2 = __builtin_bit_cast(unsigned, o0[2] * rinv) + 0x8000u;
        unsigned x3 = __builtin_bit_cast(unsigned, o0[3] * rinv) + 0x8000u;
        uint2 w0;
        w0.x = __builtin_amdgcn_perm(x1, x0, 0x07060302u);
        w0.y = __builtin_amdgcn_perm(x3, x2, 0x07060302u);
        unsigned y0 = __builtin_bit_cast(unsigned, o1[0] * rinv) + 0x8000u;
        unsigned y1 = __builtin_bit_cast(unsigned, o1[1] * rinv) + 0x8000u;
        unsigned y2 = __builtin_bit_cast(unsigned, o1[2] * rinv) + 0x8000u;
        unsigned y3 = __builtin_bit_cast(unsigned, o1[3] * rinv) + 0x8000u;
        uint2 w1;
        w1.x = __builtin_amdgcn_perm(y1, y0, 0x07060302u);
        w1.y = __builtin_amdgcn_perm(y3, y2, 0x07060302u);

        u16* orow = qo_ws + base + (size_t)(jbase + l15) * 512;
        *reinterpret_cast<uint2*>(orow + g * 4) = w0;
        *reinterpret_cast<uint2*>(orow + 16 + g * 4) = w1;
    }
}

// ---------------- Kernel 3: output projection + residual ----------------
// 512 blocks of 128 rows x 128 cols, K=512 in 4 steps. Swapped operands ->
// float4 stores fused with residual + bias.
__global__ __launch_bounds__(256) void outproj(const u16* __restrict__ o_ws,
                                               const u16* __restrict__ wo_t,
                                               const float* __restrict__ pair,
                                               const float* __restrict__ bo,
                                               float* __restrict__ out) {
    __shared__ u16 As[128 * 128];
    __shared__ u16 Bs[128 * 128];
    const int tid = threadIdx.x;
    const int wave = tid >> 6, lane = tid & 63;
    const int g = lane >> 4, l15 = lane & 15;
    const int m0 = blockIdx.x * 128;

    f32x4 acc[2][8];
    for (int rf = 0; rf < 2; ++rf)
        for (int cf = 0; cf < 8; ++cf) acc[rf][cf] = f32x4{0.f, 0.f, 0.f, 0.f};

    for (int kt = 0; kt < 4; ++kt) {
        if (kt) __syncthreads();
        const char* ab = (const char*)o_ws + ((size_t)m0 * 512 + kt * 128) * 2;
        const char* wb = (const char*)wo_t + (size_t)kt * 256;
        for (int it = 0; it < 8; ++it) {
            const int chunk = wave * 8 + it;
            const int row = chunk * 4 + (lane >> 4);
            const int col = (lane & 15) ^ (row & 7);
            gll16(ab + (size_t)row * 1024 + col * 16, (void*)(As + chunk * 512));
            gll16(wb + (size_t)row * 1024 + col * 16, (void*)(Bs + chunk * 512));
        }
        __syncthreads();

        for (int kk = 0; kk < 4; ++kk) {
            s16x8 a[2], b[8];
            for (int rf = 0; rf < 2; ++rf) {
                const int row = wave * 32 + rf * 16 + l15;
                const int ch = (kk * 4 + g) ^ (row & 7);
                a[rf] = *reinterpret_cast<s16x8*>(&As[row * 128 + ch * 8]);
            }
            for (int cf = 0; cf < 8; ++cf) {
                const int n = cf * 16 + l15;
                const int ch = (kk * 4 + g) ^ (n & 7);
                b[cf] = *reinterpret_cast<s16x8*>(&Bs[n * 128 + ch * 8]);
            }
            for (int rf = 0; rf < 2; ++rf)
                for (int cf = 0; cf < 8; ++cf)
                    acc[rf][cf] = __builtin_amdgcn_mfma_f32_16x16x32_bf16(b[cf], a[rf], acc[rf][cf], 0, 0, 0);
        }
    }

    for (int rf = 0; rf < 2; ++rf) {
        const size_t row = m0 + wave * 32 + rf * 16 + l15;
        for (int cf = 0; cf < 8; ++cf) {
            const int col = cf * 16 + g * 4;
            const float4 p = *reinterpret_cast<const float4*>(pair + row * 128 + col);
            const float4 bb = *reinterpret_cast<const float4*>(bo + col);
            float4 o;
            o.x = acc[rf][cf][0] + bb.x + p.x;
            o.y = acc[rf][cf][1] + bb.y + p.y;
            o.z = acc[rf][cf][2] + bb.z + p.z;
            o.w = acc[rf][cf][3] + bb.w + p.w;
            *reinterpret_cast<float4*>(out + row * 128 + col) = o;
        }
    }
}

extern "C" void kernel_launch(void* const* d_in, const int* in_sizes, int n_in,
                              void* d_out, int out_size, void* d_ws, size_t ws_size,
                              hipStream_t stream) {
    const float* pair = (const float*)d_in[0];
    const float* Wq = (const float*)d_in[1];
    const float* bq = (const float*)d_in[2];
    const float* Wk = (const float*)d_in[3];
    const float* bk = (const float*)d_in[4];
    const float* Wv = (const float*)d_in[5];
    const float* bv = (const float*)d_in[6];
    const float* Wo = (const float*)d_in[7];
    const float* bo = (const float*)d_in[8];
    float* out = (float*)d_out;

    char* ws = (char*)d_ws;
    u16* q_ws  = (u16*)(ws);                       // 64 MiB (q, later aliased as o)
    u16* k_ws  = (u16*)(ws + 67108864);            // 64 MiB
    u16* vT_ws = (u16*)(ws + 134217728);           // 64 MiB
    u16* wq_t  = (u16*)(ws + 201326592);           // 4 x 128 KiB
    u16* wk_t  = wq_t + 65536;
    u16* wv_t  = wk_t + 65536;
    u16* wo_t  = wv_t + 65536;
    u16* pairb = (u16*)(ws + 201326592 + 524288);  // 16 MiB
    const bool pb = ws_size >= (size_t)201326592 + 524288 + 16777216;

    wconv<<<1024, 256, 0, stream>>>(Wq, Wk, Wv, Wo, wq_t, wk_t, wv_t, wo_t);
    if (pb) {
        prep_pair<<<4096, 256, 0, stream>>>(pair, pairb);
        qkv_proj<true><<<6144, 256, 0, stream>>>(pair, pairb, wq_t, wk_t, wv_t,
                                                 bq, bk, bv, q_ws, k_ws, vT_ws);
    } else {
        qkv_proj<false><<<6144, 256, 0, stream>>>(pair, pairb, wq_t, wk_t, wv_t,
                                                  bq, bk, bv, q_ws, k_ws, vT_ws);
    }
    attn<<<4096, 256, 0, stream>>>(k_ws, vT_ws, q_ws);
    outproj<<<512, 256, 0, stream>>>(q_ws, wo_t, pair, bo, out);
}

// Round 5
// 136.784 us; speedup vs baseline: 1.2736x; 1.2736x over previous
//
#include <hip/hip_runtime.h>
#include <hip/hip_bf16.h>

#define NRES 256
#define DPAIR 128
#define NHEADS 16
#define DHEAD 32
#define DINNER 512

typedef unsigned short u16;
typedef __attribute__((ext_vector_type(4))) float f32x4;
typedef __attribute__((ext_vector_type(8))) short s16x8;
typedef __attribute__((ext_vector_type(4))) short s16x4;

// (1/sqrt(32)) * log2(e): folded into q so softmax can use exp2 directly.
#define QSCALE (0.17677669529663687f * 1.4426950408889634f)

__device__ __forceinline__ u16 f32_to_bf16(float f) {
    unsigned int u = __builtin_bit_cast(unsigned int, f);
    unsigned int r = (u + 0x7FFFu + ((u >> 16) & 1u)) >> 16;
    return (u16)r;
}

__device__ __forceinline__ float fast_exp2(float x) {
#if __has_builtin(__builtin_amdgcn_exp2f)
    return __builtin_amdgcn_exp2f(x);
#else
    return exp2f(x);
#endif
}

__device__ __forceinline__ f32x4 mfma_16x16x16_bf16(s16x4 a, s16x4 b, f32x4 c) {
#if __has_builtin(__builtin_amdgcn_mfma_f32_16x16x16bf16_1k)
    return __builtin_amdgcn_mfma_f32_16x16x16bf16_1k(a, b, c, 0, 0, 0);
#elif __has_builtin(__builtin_amdgcn_mfma_f32_16x16x16_bf16)
    return __builtin_amdgcn_mfma_f32_16x16x16_bf16(a, b, c, 0, 0, 0);
#else
    f32x4 d;
    asm volatile("v_mfma_f32_16x16x16_bf16 %0, %1, %2, %3"
                 : "=v"(d) : "v"(a), "v"(b), "v"(c));
    return d;
#endif
}

// async global->LDS, 16B per lane. LDS dest is wave-uniform base + lane*16.
__device__ __forceinline__ void gll16(const void* g, void* l) {
    __builtin_amdgcn_global_load_lds(
        (__attribute__((address_space(1))) unsigned int*)(uintptr_t)g,
        (__attribute__((address_space(3))) unsigned int*)(unsigned int)(uintptr_t)l,
        16, 0, 0);
}

// ---------------- prep: pair f32 -> bf16 ----------------
__global__ __launch_bounds__(256) void prep_pair(const float* __restrict__ pair,
                                                 u16* __restrict__ pairb) {
    const int id = blockIdx.x * 256 + threadIdx.x;   // 1048576 ids x 8 elems
    const float4* s = reinterpret_cast<const float4*>(pair) + (size_t)id * 2;
    const float4 v0 = s[0], v1 = s[1];
    ushort4 lo, hi;
    lo.x = f32_to_bf16(v0.x); lo.y = f32_to_bf16(v0.y);
    lo.z = f32_to_bf16(v0.z); lo.w = f32_to_bf16(v0.w);
    hi.x = f32_to_bf16(v1.x); hi.y = f32_to_bf16(v1.y);
    hi.z = f32_to_bf16(v1.z); hi.w = f32_to_bf16(v1.w);
    ushort4* d = reinterpret_cast<ushort4*>(pairb + (size_t)id * 8);
    d[0] = lo; d[1] = hi;
}

// ---------------- weight convert + transpose to bf16 ----------------
__global__ __launch_bounds__(256) void wconv(const float* __restrict__ Wq,
                                             const float* __restrict__ Wk,
                                             const float* __restrict__ Wv,
                                             const float* __restrict__ Wo,
                                             u16* wq_t, u16* wk_t, u16* wv_t, u16* wo_t) {
    int id = blockIdx.x * 256 + threadIdx.x;
    if (id < 3 * 65536) {
        int m = id / 65536;
        int e = id % 65536;
        int k = e >> 9, n = e & 511;
        const float* W = (m == 0) ? Wq : ((m == 1) ? Wk : Wv);
        u16* Wt = (m == 0) ? wq_t : ((m == 1) ? wk_t : wv_t);
        Wt[n * 128 + k] = f32_to_bf16(W[e]);
    } else {
        int e = id - 3 * 65536;
        int k = e >> 7, n = e & 127;
        wo_t[n * 512 + k] = f32_to_bf16(Wo[e]);
    }
}

// ---------------- Fused QKV-projection + triangular attention per (i,h) ----------------
// 512 threads = 8 waves (geometry requires exactly 8!).
// Stage pair[i] (64K) + W head-slices (24K) -> compute q,k,vT into LDS -> attention
// entirely from LDS -> write only o to global. q/k/vT never touch HBM.
__global__ __launch_bounds__(512, 2) void fused_attn(const u16* __restrict__ pairb,
                                                     const u16* __restrict__ wq_t,
                                                     const u16* __restrict__ wk_t,
                                                     const u16* __restrict__ wv_t,
                                                     const float* __restrict__ bq,
                                                     const float* __restrict__ bk,
                                                     const float* __restrict__ bv,
                                                     u16* __restrict__ o_ws) {
    __shared__ u16 pairS[256 * 128];   // linear, source-XOR-swizzled by (row&7)
    __shared__ u16 wS[3 * 32 * 128];   // [m][c][k] linear, XOR by (c&7)
    __shared__ u16 qS[256 * 40];       // [j][c] pitch 40
    __shared__ u16 kS[256 * 40];
    __shared__ u16 vTS[32 * 264];      // [c][j] pitch 264

    // XCD swizzle: the 16 h-blocks of one i stay on one XCD (pair tile L2-shared).
    const int bx = ((blockIdx.x & 7) << 9) | (blockIdx.x >> 3);
    const int i = bx >> 4, h = bx & 15;
    const int tid = threadIdx.x;
    const int wave = tid >> 6, lane = tid & 63;   // wave 0..7
    const int g = lane >> 4, l15 = lane & 15;

    // ---- stage pair tile: 64 chunks x 1024B, 8 per wave, source pre-swizzled ----
    {
        const char* pb = (const char*)(pairb + (size_t)i * 256 * 128);
        for (int it = 0; it < 8; ++it) {
            const int chunk = wave * 8 + it;          // 0..63
            const int row = chunk * 4 + (lane >> 4);
            const int col = (lane & 15) ^ (row & 7);
            gll16(pb + row * 256 + col * 16, (void*)(pairS + chunk * 512));
        }
        // ---- stage W slices: 3 x 8KiB = 24 chunks, 3 per wave ----
        for (int it = 0; it < 3; ++it) {
            const int chunk = wave * 3 + it;          // 0..23
            const int m = chunk >> 3;
            const int lc = chunk & 7;
            const u16* Wt = (m == 0) ? wq_t : ((m == 1) ? wk_t : wv_t);
            const int c = lc * 4 + (lane >> 4);       // 0..31 within slice
            const int col = (lane & 15) ^ (c & 7);
            gll16((const char*)(Wt + (size_t)(h * 32) * 128) + c * 256 + col * 16,
                  (void*)(wS + (m * 32 + lc * 4) * 128));
        }
    }
    __syncthreads();

    // ---- QKV mini-GEMM: wave owns 32 j-rows x all 32 cols, K=128 ----
    {
        const int j0 = wave * 32;                     // 8 waves -> rows 0..255
        f32x4 aq[2][2], ak[2][2], av[2][2];   // q/k: [cf][jf] (swapped); v: [jf][cf]
        for (int a = 0; a < 2; ++a)
            for (int b = 0; b < 2; ++b) {
                aq[a][b] = f32x4{0.f, 0.f, 0.f, 0.f};
                ak[a][b] = f32x4{0.f, 0.f, 0.f, 0.f};
                av[a][b] = f32x4{0.f, 0.f, 0.f, 0.f};
            }
        for (int kk = 0; kk < 4; ++kk) {
            s16x8 pf[2], wf[3][2];
            for (int jf = 0; jf < 2; ++jf) {
                const int row = j0 + jf * 16 + l15;
                const int ch = (kk * 4 + g) ^ (row & 7);
                pf[jf] = *reinterpret_cast<s16x8*>(&pairS[row * 128 + ch * 8]);
            }
            for (int m = 0; m < 3; ++m)
                for (int cf = 0; cf < 2; ++cf) {
                    const int c = cf * 16 + l15;
                    const int ch = (kk * 4 + g) ^ (c & 7);
                    wf[m][cf] = *reinterpret_cast<s16x8*>(&wS[(m * 32 + c) * 128 + ch * 8]);
                }
            for (int cf = 0; cf < 2; ++cf)
                for (int jf = 0; jf < 2; ++jf) {
                    aq[cf][jf] = __builtin_amdgcn_mfma_f32_16x16x32_bf16(wf[0][cf], pf[jf], aq[cf][jf], 0, 0, 0);
                    ak[cf][jf] = __builtin_amdgcn_mfma_f32_16x16x32_bf16(wf[1][cf], pf[jf], ak[cf][jf], 0, 0, 0);
                    av[jf][cf] = __builtin_amdgcn_mfma_f32_16x16x32_bf16(pf[jf], wf[2][cf], av[jf][cf], 0, 0, 0);
                }
        }
        // epilogue: q/k lane holds [j=j0+jf*16+l15][c=cf*16+g*4+(0..3)] -> ushort4
        for (int cf = 0; cf < 2; ++cf) {
            const int c = cf * 16 + g * 4;
            const float4 b4q = *reinterpret_cast<const float4*>(bq + h * 32 + c);
            const float4 b4k = *reinterpret_cast<const float4*>(bk + h * 32 + c);
            for (int jf = 0; jf < 2; ++jf) {
                const int j = j0 + jf * 16 + l15;
                ushort4 oq, ok;
                oq.x = f32_to_bf16((aq[cf][jf][0] + b4q.x) * QSCALE);
                oq.y = f32_to_bf16((aq[cf][jf][1] + b4q.y) * QSCALE);
                oq.z = f32_to_bf16((aq[cf][jf][2] + b4q.z) * QSCALE);
                oq.w = f32_to_bf16((aq[cf][jf][3] + b4q.w) * QSCALE);
                *reinterpret_cast<ushort4*>(&qS[j * 40 + c]) = oq;
                ok.x = f32_to_bf16(ak[cf][jf][0] + b4k.x);
                ok.y = f32_to_bf16(ak[cf][jf][1] + b4k.y);
                ok.z = f32_to_bf16(ak[cf][jf][2] + b4k.z);
                ok.w = f32_to_bf16(ak[cf][jf][3] + b4k.w);
                *reinterpret_cast<ushort4*>(&kS[j * 40 + c]) = ok;
            }
        }
        // v: lane holds [j=j0+jf*16+g*4+(0..3)][c=cf*16+l15] -> vTS[c][j] ushort4
        for (int cf = 0; cf < 2; ++cf) {
            const int c = cf * 16 + l15;
            const float bvv = bv[h * 32 + c];
            for (int jf = 0; jf < 2; ++jf) {
                const int j = j0 + jf * 16 + g * 4;
                ushort4 ov;
                ov.x = f32_to_bf16(av[jf][cf][0] + bvv);
                ov.y = f32_to_bf16(av[jf][cf][1] + bvv);
                ov.z = f32_to_bf16(av[jf][cf][2] + bvv);
                ov.w = f32_to_bf16(av[jf][cf][3] + bvv);
                *reinterpret_cast<ushort4*>(&vTS[c * 264 + j]) = ov;
            }
        }
    }
    __syncthreads();

    // ---- attention: 8 waves x 2 j-tiles = exact cover; per-wave masked work
    // (wave+1)+(16-wave)=17 k-tiles, perfectly balanced.
    const size_t obase = ((size_t)i * 256) * 512 + h * 32;

    for (int ch2 = 0; ch2 < 2; ++ch2) {
        const int t = (ch2 == 0) ? wave : (15 - wave);
        const int jbase = t * 16;
        const int ktmax = t + 1;

        const s16x8 qf = *reinterpret_cast<const s16x8*>(&qS[(jbase + l15) * 40 + g * 8]);

        f32x4 o0 = {0.f, 0.f, 0.f, 0.f}, o1 = {0.f, 0.f, 0.f, 0.f};
        float sum = 0.f;

        for (int kt = 0; kt < ktmax; ++kt) {
            const s16x8 kf = *reinterpret_cast<s16x8*>(&kS[(kt * 16 + l15) * 40 + g * 8]);
            f32x4 s = __builtin_amdgcn_mfma_f32_16x16x32_bf16(kf, qf, f32x4{0.f, 0.f, 0.f, 0.f}, 0, 0, 0);
            // s[r] = S[k = kt*16 + g*4 + r][j = jbase+l15] (log2 domain)
            float p0, p1, p2, p3;
            if (kt == t) {  // diagonal tile: mask k > j
                p0 = ((g * 4 + 0) > l15) ? 0.f : fast_exp2(s[0]);
                p1 = ((g * 4 + 1) > l15) ? 0.f : fast_exp2(s[1]);
                p2 = ((g * 4 + 2) > l15) ? 0.f : fast_exp2(s[2]);
                p3 = ((g * 4 + 3) > l15) ? 0.f : fast_exp2(s[3]);
            } else {
                p0 = fast_exp2(s[0]); p1 = fast_exp2(s[1]);
                p2 = fast_exp2(s[2]); p3 = fast_exp2(s[3]);
            }
            sum += (p0 + p1) + (p2 + p3);
            unsigned e0 = __builtin_bit_cast(unsigned, p0) + 0x8000u;
            unsigned e1 = __builtin_bit_cast(unsigned, p1) + 0x8000u;
            unsigned e2 = __builtin_bit_cast(unsigned, p2) + 0x8000u;
            unsigned e3 = __builtin_bit_cast(unsigned, p3) + 0x8000u;
            uint2 pw;
            pw.x = __builtin_amdgcn_perm(e1, e0, 0x07060302u);
            pw.y = __builtin_amdgcn_perm(e3, e2, 0x07060302u);
            const s16x4 pb = __builtin_bit_cast(s16x4, pw);
            const s16x4 va0 = *reinterpret_cast<s16x4*>(&vTS[l15 * 264 + kt * 16 + g * 4]);
            const s16x4 va1 = *reinterpret_cast<s16x4*>(&vTS[(16 + l15) * 264 + kt * 16 + g * 4]);
            o0 = mfma_16x16x16_bf16(va0, pb, o0);
            o1 = mfma_16x16x16_bf16(va1, pb, o1);
        }

        sum += __shfl_xor(sum, 16, 64);
        sum += __shfl_xor(sum, 32, 64);
        const float rinv = 1.0f / sum;

        unsigned x0 = __builtin_bit_cast(unsigned, o0[0] * rinv) + 0x8000u;
        unsigned x1 = __builtin_bit_cast(unsigned, o0[1] * rinv) + 0x8000u;
        unsigned x2 = __builtin_bit_cast(unsigned, o0[2] * rinv) + 0x8000u;
        unsigned x3 = __builtin_bit_cast(unsigned, o0[3] * rinv) + 0x8000u;
        uint2 w0;
        w0.x = __builtin_amdgcn_perm(x1, x0, 0x07060302u);
        w0.y = __builtin_amdgcn_perm(x3, x2, 0x07060302u);
        unsigned y0 = __builtin_bit_cast(unsigned, o1[0] * rinv) + 0x8000u;
        unsigned y1 = __builtin_bit_cast(unsigned, o1[1] * rinv) + 0x8000u;
        unsigned y2 = __builtin_bit_cast(unsigned, o1[2] * rinv) + 0x8000u;
        unsigned y3 = __builtin_bit_cast(unsigned, o1[3] * rinv) + 0x8000u;
        uint2 w1;
        w1.x = __builtin_amdgcn_perm(y1, y0, 0x07060302u);
        w1.y = __builtin_amdgcn_perm(y3, y2, 0x07060302u);

        u16* orow = o_ws + obase + (size_t)(jbase + l15) * 512;
        *reinterpret_cast<uint2*>(orow + g * 4) = w0;
        *reinterpret_cast<uint2*>(orow + 16 + g * 4) = w1;
    }
}

// ---------------- output projection + residual (round-2 structure) ----------------
__global__ __launch_bounds__(256) void outproj(const u16* __restrict__ o_ws,
                                               const u16* __restrict__ wo_t,
                                               const float* __restrict__ pair,
                                               const float* __restrict__ bo,
                                               float* __restrict__ out) {
    __shared__ u16 As[64 * 72];
    __shared__ u16 Bs[128 * 72];
    const int tid = threadIdx.x;
    const int m0 = blockIdx.x * 64;
    const int wave = tid >> 6, lane = tid & 63;
    const int g = lane >> 4, l15 = lane & 15;

    f32x4 acc[8];
    for (int c = 0; c < 8; ++c) acc[c] = f32x4{0.f, 0.f, 0.f, 0.f};

    for (int kt = 0; kt < 8; ++kt) {
        __syncthreads();
        for (int it = 0; it < 2; ++it) {
            int L = tid + it * 256;
            int row = L >> 3, seg = L & 7;
            *reinterpret_cast<s16x8*>(&As[row * 72 + seg * 8]) =
                *reinterpret_cast<const s16x8*>(o_ws + (size_t)(m0 + row) * 512 + kt * 64 + seg * 8);
        }
        for (int it = 0; it < 4; ++it) {
            int L = tid + it * 256;
            int n = L >> 3, seg = L & 7;
            *reinterpret_cast<s16x8*>(&Bs[n * 72 + seg * 8]) =
                *reinterpret_cast<const s16x8*>(wo_t + (size_t)n * 512 + kt * 64 + seg * 8);
        }
        __syncthreads();
        for (int kk = 0; kk < 2; ++kk) {
            const s16x8 a = *reinterpret_cast<s16x8*>(&As[(wave * 16 + l15) * 72 + kk * 32 + g * 8]);
            for (int c = 0; c < 8; ++c) {
                const s16x8 b = *reinterpret_cast<s16x8*>(&Bs[(c * 16 + l15) * 72 + kk * 32 + g * 8]);
                acc[c] = __builtin_amdgcn_mfma_f32_16x16x32_bf16(a, b, acc[c], 0, 0, 0);
            }
        }
    }

    for (int c = 0; c < 8; ++c) {
        const int n = c * 16 + l15;
        const float bias = bo[n];
        for (int r = 0; r < 4; ++r) {
            const size_t row = m0 + wave * 16 + g * 4 + r;
            out[row * 128 + n] = acc[c][r] + bias + pair[row * 128 + n];
        }
    }
}

extern "C" void kernel_launch(void* const* d_in, const int* in_sizes, int n_in,
                              void* d_out, int out_size, void* d_ws, size_t ws_size,
                              hipStream_t stream) {
    const float* pair = (const float*)d_in[0];
    const float* Wq = (const float*)d_in[1];
    const float* bq = (const float*)d_in[2];
    const float* Wk = (const float*)d_in[3];
    const float* bk = (const float*)d_in[4];
    const float* Wv = (const float*)d_in[5];
    const float* bv = (const float*)d_in[6];
    const float* Wo = (const float*)d_in[7];
    const float* bo = (const float*)d_in[8];
    float* out = (float*)d_out;

    char* ws = (char*)d_ws;
    u16* o_ws  = (u16*)(ws);                       // 64 MiB
    u16* wq_t  = (u16*)(ws + 67108864);            // 128 KiB each
    u16* wk_t  = wq_t + 65536;
    u16* wv_t  = wk_t + 65536;
    u16* wo_t  = wv_t + 65536;
    u16* pairb = (u16*)(ws + 67108864 + 1048576);  // 16 MiB

    wconv<<<1024, 256, 0, stream>>>(Wq, Wk, Wv, Wo, wq_t, wk_t, wv_t, wo_t);
    prep_pair<<<4096, 256, 0, stream>>>(pair, pairb);
    fused_attn<<<4096, 512, 0, stream>>>(pairb, wq_t, wk_t, wv_t, bq, bk, bv, o_ws);
    outproj<<<1024, 256, 0, stream>>>(o_ws, wo_t, pair, bo, out);
}

// Round 6
// 119.008 us; speedup vs baseline: 1.4639x; 1.1494x over previous
//
#include <hip/hip_runtime.h>
#include <hip/hip_bf16.h>

#define NRES 256
#define DPAIR 128
#define NHEADS 16
#define DHEAD 32
#define DINNER 512

typedef unsigned short u16;
typedef __attribute__((ext_vector_type(4))) float f32x4;
typedef __attribute__((ext_vector_type(8))) short s16x8;
typedef __attribute__((ext_vector_type(4))) short s16x4;

// (1/sqrt(32)) * log2(e): folded into q so softmax can use exp2 directly.
#define QSCALE (0.17677669529663687f * 1.4426950408889634f)

__device__ __forceinline__ u16 f32_to_bf16(float f) {
    unsigned int u = __builtin_bit_cast(unsigned int, f);
    unsigned int r = (u + 0x7FFFu + ((u >> 16) & 1u)) >> 16;
    return (u16)r;
}

__device__ __forceinline__ float fast_exp2(float x) {
#if __has_builtin(__builtin_amdgcn_exp2f)
    return __builtin_amdgcn_exp2f(x);
#else
    return exp2f(x);
#endif
}

__device__ __forceinline__ f32x4 mfma_16x16x16_bf16(s16x4 a, s16x4 b, f32x4 c) {
#if __has_builtin(__builtin_amdgcn_mfma_f32_16x16x16bf16_1k)
    return __builtin_amdgcn_mfma_f32_16x16x16bf16_1k(a, b, c, 0, 0, 0);
#elif __has_builtin(__builtin_amdgcn_mfma_f32_16x16x16_bf16)
    return __builtin_amdgcn_mfma_f32_16x16x16_bf16(a, b, c, 0, 0, 0);
#else
    f32x4 d;
    asm volatile("v_mfma_f32_16x16x16_bf16 %0, %1, %2, %3"
                 : "=v"(d) : "v"(a), "v"(b), "v"(c));
    return d;
#endif
}

// async global->LDS, 16B per lane. LDS dest is wave-uniform base + lane*16.
__device__ __forceinline__ void gll16(const void* g, void* l) {
    __builtin_amdgcn_global_load_lds(
        (__attribute__((address_space(1))) unsigned int*)(uintptr_t)g,
        (__attribute__((address_space(3))) unsigned int*)(unsigned int)(uintptr_t)l,
        16, 0, 0);
}

// ---------------- prep: pair f32 -> bf16 ----------------
__global__ __launch_bounds__(256) void prep_pair(const float* __restrict__ pair,
                                                 u16* __restrict__ pairb) {
    const int id = blockIdx.x * 256 + threadIdx.x;   // 1048576 ids x 8 elems
    const float4* s = reinterpret_cast<const float4*>(pair) + (size_t)id * 2;
    const float4 v0 = s[0], v1 = s[1];
    ushort4 lo, hi;
    lo.x = f32_to_bf16(v0.x); lo.y = f32_to_bf16(v0.y);
    lo.z = f32_to_bf16(v0.z); lo.w = f32_to_bf16(v0.w);
    hi.x = f32_to_bf16(v1.x); hi.y = f32_to_bf16(v1.y);
    hi.z = f32_to_bf16(v1.z); hi.w = f32_to_bf16(v1.w);
    ushort4* d = reinterpret_cast<ushort4*>(pairb + (size_t)id * 8);
    d[0] = lo; d[1] = hi;
}

// ---------------- weight convert + transpose to bf16 ----------------
__global__ __launch_bounds__(256) void wconv(const float* __restrict__ Wq,
                                             const float* __restrict__ Wk,
                                             const float* __restrict__ Wv,
                                             const float* __restrict__ Wo,
                                             u16* wq_t, u16* wk_t, u16* wv_t, u16* wo_t) {
    int id = blockIdx.x * 256 + threadIdx.x;
    if (id < 3 * 65536) {
        int m = id / 65536;
        int e = id % 65536;
        int k = e >> 9, n = e & 511;
        const float* W = (m == 0) ? Wq : ((m == 1) ? Wk : Wv);
        u16* Wt = (m == 0) ? wq_t : ((m == 1) ? wk_t : wv_t);
        Wt[n * 128 + k] = f32_to_bf16(W[e]);
    } else {
        int e = id - 3 * 65536;
        int k = e >> 7, n = e & 127;
        wo_t[n * 512 + k] = f32_to_bf16(Wo[e]);
    }
}

// ---------------- Fused QKV-projection + triangular attention per (i,h) ----------------
// 512 threads = 8 waves. Pair rows live in REGISTERS (each wave only ever needs
// its own 32 rows); only W/q/k/vT go through LDS -> 78336B -> 2 blocks/CU.
__global__ __launch_bounds__(512, 4) void fused_attn(const u16* __restrict__ pairb,
                                                     const u16* __restrict__ wq_t,
                                                     const u16* __restrict__ wk_t,
                                                     const u16* __restrict__ wv_t,
                                                     const float* __restrict__ bq,
                                                     const float* __restrict__ bk,
                                                     const float* __restrict__ bv,
                                                     u16* __restrict__ o_ws) {
    __shared__ u16 wS[3 * 32 * 128];   // 24576B: [m][c][k] linear, source-XOR by (c&7)
    __shared__ u16 qS[256 * 32];       // 16384B: [j][c], 16B-chunk XOR-swizzled by (j&3)
    __shared__ u16 kS[256 * 40];       // 20480B: [j][c] pitch 40 (conflict-free reads)
    __shared__ u16 vTS[32 * 264];      // 16896B: [c][j] pitch 264

    // XCD swizzle: the 16 h-blocks of one i stay on one XCD (pair rows L2-shared).
    const int bx = ((blockIdx.x & 7) << 9) | (blockIdx.x >> 3);
    const int i = bx >> 4, h = bx & 15;
    const int tid = threadIdx.x;
    const int wave = tid >> 6, lane = tid & 63;   // wave 0..7
    const int g = lane >> 4, l15 = lane & 15;
    const int j0 = wave * 32;

    // ---- stage W slices: 3 x 8KiB = 24 chunks, 3 per wave (async to LDS) ----
    for (int it = 0; it < 3; ++it) {
        const int chunk = wave * 3 + it;          // 0..23
        const int m = chunk >> 3;
        const int lc = chunk & 7;
        const u16* Wt = (m == 0) ? wq_t : ((m == 1) ? wk_t : wv_t);
        const int c = lc * 4 + (lane >> 4);       // 0..31 within slice
        const int col = (lane & 15) ^ (c & 7);
        gll16((const char*)(Wt + (size_t)(h * 32) * 128) + c * 256 + col * 16,
              (void*)(wS + (m * 32 + lc * 4) * 128));
    }
    // ---- pair rows straight to registers (wave-private!) ----
    s16x8 pf[2][4];
    {
        const u16* prow = pairb + (size_t)(i * 256 + j0 + l15) * 128;
        #pragma unroll
        for (int jf = 0; jf < 2; ++jf)
            #pragma unroll
            for (int kk = 0; kk < 4; ++kk)
                pf[jf][kk] = *reinterpret_cast<const s16x8*>(prow + jf * 16 * 128 + kk * 32 + g * 8);
    }
    __syncthreads();   // drains gll16 (vmcnt) + barrier

    // ---- QKV mini-GEMM: wave owns 32 j-rows x all 32 cols, K=128 ----
    {
        f32x4 aq[2][2], ak[2][2], av[2][2];   // q/k: [cf][jf] (swapped); v: [jf][cf]
        #pragma unroll
        for (int a = 0; a < 2; ++a)
            #pragma unroll
            for (int b = 0; b < 2; ++b) {
                aq[a][b] = f32x4{0.f, 0.f, 0.f, 0.f};
                ak[a][b] = f32x4{0.f, 0.f, 0.f, 0.f};
                av[a][b] = f32x4{0.f, 0.f, 0.f, 0.f};
            }
        #pragma unroll
        for (int kk = 0; kk < 4; ++kk) {
            s16x8 wf[3][2];
            #pragma unroll
            for (int m = 0; m < 3; ++m)
                #pragma unroll
                for (int cf = 0; cf < 2; ++cf) {
                    const int c = cf * 16 + l15;
                    const int ch = (kk * 4 + g) ^ (c & 7);
                    wf[m][cf] = *reinterpret_cast<s16x8*>(&wS[(m * 32 + c) * 128 + ch * 8]);
                }
            #pragma unroll
            for (int cf = 0; cf < 2; ++cf)
                #pragma unroll
                for (int jf = 0; jf < 2; ++jf) {
                    aq[cf][jf] = __builtin_amdgcn_mfma_f32_16x16x32_bf16(wf[0][cf], pf[jf][kk], aq[cf][jf], 0, 0, 0);
                    ak[cf][jf] = __builtin_amdgcn_mfma_f32_16x16x32_bf16(wf[1][cf], pf[jf][kk], ak[cf][jf], 0, 0, 0);
                    av[jf][cf] = __builtin_amdgcn_mfma_f32_16x16x32_bf16(pf[jf][kk], wf[2][cf], av[jf][cf], 0, 0, 0);
                }
        }
        // epilogue: q/k lane holds [j=j0+jf*16+l15][c=cf*16+g*4+(0..3)]
        #pragma unroll
        for (int cf = 0; cf < 2; ++cf) {
            const int c = cf * 16 + g * 4;
            const float4 b4q = *reinterpret_cast<const float4*>(bq + h * 32 + c);
            const float4 b4k = *reinterpret_cast<const float4*>(bk + h * 32 + c);
            #pragma unroll
            for (int jf = 0; jf < 2; ++jf) {
                const int j = j0 + jf * 16 + l15;
                ushort4 oq, ok;
                oq.x = f32_to_bf16((aq[cf][jf][0] + b4q.x) * QSCALE);
                oq.y = f32_to_bf16((aq[cf][jf][1] + b4q.y) * QSCALE);
                oq.z = f32_to_bf16((aq[cf][jf][2] + b4q.z) * QSCALE);
                oq.w = f32_to_bf16((aq[cf][jf][3] + b4q.w) * QSCALE);
                // 16B-chunk XOR swizzle: chunk cc = 2cf + (g>>1), pos = cc ^ (j&3)
                *reinterpret_cast<ushort4*>(
                    &qS[j * 32 + (((cf << 1) + (g >> 1)) ^ (j & 3)) * 8 + (g & 1) * 4]) = oq;
                ok.x = f32_to_bf16(ak[cf][jf][0] + b4k.x);
                ok.y = f32_to_bf16(ak[cf][jf][1] + b4k.y);
                ok.z = f32_to_bf16(ak[cf][jf][2] + b4k.z);
                ok.w = f32_to_bf16(ak[cf][jf][3] + b4k.w);
                *reinterpret_cast<ushort4*>(&kS[j * 40 + c]) = ok;
            }
        }
        // v: lane holds [j=j0+jf*16+g*4+(0..3)][c=cf*16+l15] -> vTS[c][j]
        #pragma unroll
        for (int cf = 0; cf < 2; ++cf) {
            const int c = cf * 16 + l15;
            const float bvv = bv[h * 32 + c];
            #pragma unroll
            for (int jf = 0; jf < 2; ++jf) {
                const int j = j0 + jf * 16 + g * 4;
                ushort4 ov;
                ov.x = f32_to_bf16(av[jf][cf][0] + bvv);
                ov.y = f32_to_bf16(av[jf][cf][1] + bvv);
                ov.z = f32_to_bf16(av[jf][cf][2] + bvv);
                ov.w = f32_to_bf16(av[jf][cf][3] + bvv);
                *reinterpret_cast<ushort4*>(&vTS[c * 264 + j]) = ov;
            }
        }
    }
    __syncthreads();

    // ---- attention: 8 waves x 2 j-tiles = exact cover; per-wave masked work
    // (wave+1)+(16-wave)=17 k-tiles, perfectly balanced.
    const size_t obase = ((size_t)i * 256) * 512 + h * 32;

    for (int ch2 = 0; ch2 < 2; ++ch2) {
        const int t = (ch2 == 0) ? wave : (15 - wave);
        const int jbase = t * 16;
        const int ktmax = t + 1;

        // swizzled q read: chunk g stored at position g ^ (j&3); j&3 == l15&3
        const s16x8 qf = *reinterpret_cast<const s16x8*>(
            &qS[(jbase + l15) * 32 + (g ^ (l15 & 3)) * 8]);

        f32x4 oA0 = {0.f, 0.f, 0.f, 0.f}, oA1 = {0.f, 0.f, 0.f, 0.f};
        f32x4 oB0 = {0.f, 0.f, 0.f, 0.f}, oB1 = {0.f, 0.f, 0.f, 0.f};
        float sA = 0.f, sB = 0.f;

        auto body = [&](int kt, f32x4& u0, f32x4& u1, float& sm) {
            const s16x8 kf = *reinterpret_cast<s16x8*>(&kS[(kt * 16 + l15) * 40 + g * 8]);
            f32x4 s = __builtin_amdgcn_mfma_f32_16x16x32_bf16(kf, qf, f32x4{0.f, 0.f, 0.f, 0.f}, 0, 0, 0);
            // s[r] = S[k = kt*16 + g*4 + r][j = jbase+l15] (log2 domain)
            float p0, p1, p2, p3;
            if (kt == t) {  // diagonal tile: mask k > j
                p0 = ((g * 4 + 0) > l15) ? 0.f : fast_exp2(s[0]);
                p1 = ((g * 4 + 1) > l15) ? 0.f : fast_exp2(s[1]);
                p2 = ((g * 4 + 2) > l15) ? 0.f : fast_exp2(s[2]);
                p3 = ((g * 4 + 3) > l15) ? 0.f : fast_exp2(s[3]);
            } else {
                p0 = fast_exp2(s[0]); p1 = fast_exp2(s[1]);
                p2 = fast_exp2(s[2]); p3 = fast_exp2(s[3]);
            }
            sm += (p0 + p1) + (p2 + p3);
            unsigned e0 = __builtin_bit_cast(unsigned, p0) + 0x8000u;
            unsigned e1 = __builtin_bit_cast(unsigned, p1) + 0x8000u;
            unsigned e2 = __builtin_bit_cast(unsigned, p2) + 0x8000u;
            unsigned e3 = __builtin_bit_cast(unsigned, p3) + 0x8000u;
            uint2 pw;
            pw.x = __builtin_amdgcn_perm(e1, e0, 0x07060302u);
            pw.y = __builtin_amdgcn_perm(e3, e2, 0x07060302u);
            const s16x4 pb = __builtin_bit_cast(s16x4, pw);
            const s16x4 va0 = *reinterpret_cast<s16x4*>(&vTS[l15 * 264 + kt * 16 + g * 4]);
            const s16x4 va1 = *reinterpret_cast<s16x4*>(&vTS[(16 + l15) * 264 + kt * 16 + g * 4]);
            u0 = mfma_16x16x16_bf16(va0, pb, u0);
            u1 = mfma_16x16x16_bf16(va1, pb, u1);
        };

        int kt = 0;
        for (; kt + 2 <= ktmax; kt += 2) {
            body(kt, oA0, oA1, sA);
            body(kt + 1, oB0, oB1, sB);
        }
        if (kt < ktmax) body(kt, oA0, oA1, sA);

        float sum = sA + sB;
        sum += __shfl_xor(sum, 16, 64);
        sum += __shfl_xor(sum, 32, 64);
        const float rinv = 1.0f / sum;
        const f32x4 o0 = oA0 + oB0;
        const f32x4 o1 = oA1 + oB1;

        unsigned x0 = __builtin_bit_cast(unsigned, o0[0] * rinv) + 0x8000u;
        unsigned x1 = __builtin_bit_cast(unsigned, o0[1] * rinv) + 0x8000u;
        unsigned x2 = __builtin_bit_cast(unsigned, o0[2] * rinv) + 0x8000u;
        unsigned x3 = __builtin_bit_cast(unsigned, o0[3] * rinv) + 0x8000u;
        uint2 w0;
        w0.x = __builtin_amdgcn_perm(x1, x0, 0x07060302u);
        w0.y = __builtin_amdgcn_perm(x3, x2, 0x07060302u);
        unsigned y0 = __builtin_bit_cast(unsigned, o1[0] * rinv) + 0x8000u;
        unsigned y1 = __builtin_bit_cast(unsigned, o1[1] * rinv) + 0x8000u;
        unsigned y2 = __builtin_bit_cast(unsigned, o1[2] * rinv) + 0x8000u;
        unsigned y3 = __builtin_bit_cast(unsigned, o1[3] * rinv) + 0x8000u;
        uint2 w1;
        w1.x = __builtin_amdgcn_perm(y1, y0, 0x07060302u);
        w1.y = __builtin_amdgcn_perm(y3, y2, 0x07060302u);

        u16* orow = o_ws + obase + (size_t)(jbase + l15) * 512;
        *reinterpret_cast<uint2*>(orow + g * 4) = w0;
        *reinterpret_cast<uint2*>(orow + 16 + g * 4) = w1;
    }
}

// ---------------- output projection + residual ----------------
__global__ __launch_bounds__(256) void outproj(const u16* __restrict__ o_ws,
                                               const u16* __restrict__ wo_t,
                                               const float* __restrict__ pair,
                                               const float* __restrict__ bo,
                                               float* __restrict__ out) {
    __shared__ u16 As[64 * 72];
    __shared__ u16 Bs[128 * 72];
    const int tid = threadIdx.x;
    const int m0 = blockIdx.x * 64;
    const int wave = tid >> 6, lane = tid & 63;
    const int g = lane >> 4, l15 = lane & 15;

    f32x4 acc[8];
    for (int c = 0; c < 8; ++c) acc[c] = f32x4{0.f, 0.f, 0.f, 0.f};

    for (int kt = 0; kt < 8; ++kt) {
        __syncthreads();
        for (int it = 0; it < 2; ++it) {
            int L = tid + it * 256;
            int row = L >> 3, seg = L & 7;
            *reinterpret_cast<s16x8*>(&As[row * 72 + seg * 8]) =
                *reinterpret_cast<const s16x8*>(o_ws + (size_t)(m0 + row) * 512 + kt * 64 + seg * 8);
        }
        for (int it = 0; it < 4; ++it) {
            int L = tid + it * 256;
            int n = L >> 3, seg = L & 7;
            *reinterpret_cast<s16x8*>(&Bs[n * 72 + seg * 8]) =
                *reinterpret_cast<const s16x8*>(wo_t + (size_t)n * 512 + kt * 64 + seg * 8);
        }
        __syncthreads();
        for (int kk = 0; kk < 2; ++kk) {
            const s16x8 a = *reinterpret_cast<s16x8*>(&As[(wave * 16 + l15) * 72 + kk * 32 + g * 8]);
            for (int c = 0; c < 8; ++c) {
                const s16x8 b = *reinterpret_cast<s16x8*>(&Bs[(c * 16 + l15) * 72 + kk * 32 + g * 8]);
                acc[c] = __builtin_amdgcn_mfma_f32_16x16x32_bf16(a, b, acc[c], 0, 0, 0);
            }
        }
    }

    for (int c = 0; c < 8; ++c) {
        const int n = c * 16 + l15;
        const float bias = bo[n];
        for (int r = 0; r < 4; ++r) {
            const size_t row = m0 + wave * 16 + g * 4 + r;
            out[row * 128 + n] = acc[c][r] + bias + pair[row * 128 + n];
        }
    }
}

extern "C" void kernel_launch(void* const* d_in, const int* in_sizes, int n_in,
                              void* d_out, int out_size, void* d_ws, size_t ws_size,
                              hipStream_t stream) {
    const float* pair = (const float*)d_in[0];
    const float* Wq = (const float*)d_in[1];
    const float* bq = (const float*)d_in[2];
    const float* Wk = (const float*)d_in[3];
    const float* bk = (const float*)d_in[4];
    const float* Wv = (const float*)d_in[5];
    const float* bv = (const float*)d_in[6];
    const float* Wo = (const float*)d_in[7];
    const float* bo = (const float*)d_in[8];
    float* out = (float*)d_out;

    char* ws = (char*)d_ws;
    u16* o_ws  = (u16*)(ws);                       // 64 MiB
    u16* wq_t  = (u16*)(ws + 67108864);            // 128 KiB each
    u16* wk_t  = wq_t + 65536;
    u16* wv_t  = wk_t + 65536;
    u16* wo_t  = wv_t + 65536;
    u16* pairb = (u16*)(ws + 67108864 + 1048576);  // 16 MiB

    wconv<<<1024, 256, 0, stream>>>(Wq, Wk, Wv, Wo, wq_t, wk_t, wv_t, wo_t);
    prep_pair<<<4096, 256, 0, stream>>>(pair, pairb);
    fused_attn<<<4096, 512, 0, stream>>>(pairb, wq_t, wk_t, wv_t, bq, bk, bv, o_ws);
    outproj<<<1024, 256, 0, stream>>>(o_ws, wo_t, pair, bo, out);
}

// Round 8
// 114.127 us; speedup vs baseline: 1.5265x; 1.0428x over previous
//
#include <hip/hip_runtime.h>
#include <hip/hip_bf16.h>

#define NRES 256
#define DPAIR 128
#define NHEADS 16
#define DHEAD 32
#define DINNER 512

typedef unsigned short u16;
typedef __attribute__((ext_vector_type(4))) float f32x4;
typedef __attribute__((ext_vector_type(8))) short s16x8;
typedef __attribute__((ext_vector_type(4))) short s16x4;

// (1/sqrt(32)) * log2(e): folded into q so softmax can use exp2 directly.
#define QSCALE (0.17677669529663687f * 1.4426950408889634f)

__device__ __forceinline__ u16 f32_to_bf16(float f) {
    unsigned int u = __builtin_bit_cast(unsigned int, f);
    unsigned int r = (u + 0x7FFFu + ((u >> 16) & 1u)) >> 16;
    return (u16)r;
}

__device__ __forceinline__ float fast_exp2(float x) {
#if __has_builtin(__builtin_amdgcn_exp2f)
    return __builtin_amdgcn_exp2f(x);
#else
    return exp2f(x);
#endif
}

__device__ __forceinline__ f32x4 mfma_16x16x16_bf16(s16x4 a, s16x4 b, f32x4 c) {
#if __has_builtin(__builtin_amdgcn_mfma_f32_16x16x16bf16_1k)
    return __builtin_amdgcn_mfma_f32_16x16x16bf16_1k(a, b, c, 0, 0, 0);
#elif __has_builtin(__builtin_amdgcn_mfma_f32_16x16x16_bf16)
    return __builtin_amdgcn_mfma_f32_16x16x16_bf16(a, b, c, 0, 0, 0);
#else
    f32x4 d;
    asm volatile("v_mfma_f32_16x16x16_bf16 %0, %1, %2, %3"
                 : "=v"(d) : "v"(a), "v"(b), "v"(c));
    return d;
#endif
}

// async global->LDS, 16B per lane. LDS dest is wave-uniform base + lane*16.
__device__ __forceinline__ void gll16(const void* g, void* l) {
    __builtin_amdgcn_global_load_lds(
        (__attribute__((address_space(1))) unsigned int*)(uintptr_t)g,
        (__attribute__((address_space(3))) unsigned int*)(unsigned int)(uintptr_t)l,
        16, 0, 0);
}

// ---------------- prep: weight convert/transpose + pair f32->bf16 (merged) ----------------
__global__ __launch_bounds__(256) void prep_all(const float* __restrict__ Wq,
                                                const float* __restrict__ Wk,
                                                const float* __restrict__ Wv,
                                                const float* __restrict__ Wo,
                                                const float* __restrict__ pair,
                                                u16* wq_t, u16* wk_t, u16* wv_t, u16* wo_t,
                                                u16* __restrict__ pairb) {
    const int b = blockIdx.x;
    if (b < 1024) {
        int id = b * 256 + threadIdx.x;
        if (id < 3 * 65536) {
            int m = id / 65536;
            int e = id % 65536;
            int k = e >> 9, n = e & 511;
            const float* W = (m == 0) ? Wq : ((m == 1) ? Wk : Wv);
            u16* Wt = (m == 0) ? wq_t : ((m == 1) ? wk_t : wv_t);
            Wt[n * 128 + k] = f32_to_bf16(W[e]);
        } else {
            int e = id - 3 * 65536;
            int k = e >> 7, n = e & 127;
            wo_t[n * 512 + k] = f32_to_bf16(Wo[e]);
        }
    } else {
        const int id = (b - 1024) * 256 + threadIdx.x;   // 1048576 ids x 8 elems
        const float4* s = reinterpret_cast<const float4*>(pair) + (size_t)id * 2;
        const float4 v0 = s[0], v1 = s[1];
        ushort4 lo, hi;
        lo.x = f32_to_bf16(v0.x); lo.y = f32_to_bf16(v0.y);
        lo.z = f32_to_bf16(v0.z); lo.w = f32_to_bf16(v0.w);
        hi.x = f32_to_bf16(v1.x); hi.y = f32_to_bf16(v1.y);
        hi.z = f32_to_bf16(v1.z); hi.w = f32_to_bf16(v1.w);
        ushort4* d = reinterpret_cast<ushort4*>(pairb + (size_t)id * 8);
        d[0] = lo; d[1] = hi;
    }
}

// ---------------- Fused QKV-projection + triangular attention per (i,h) ----------------
// 512 threads = 8 waves. Pair rows in registers; W/q/k/vT in LDS (78336B, 2 blk/CU).
// Attention: chunks t=wave and t=15-wave INTERLEAVED in one kt loop — shared
// kS/vTS reads (A's kt range is a subset of B's), two independent MFMA/VALU chains.
__global__ __launch_bounds__(512, 4) void fused_attn(const u16* __restrict__ pairb,
                                                     const u16* __restrict__ wq_t,
                                                     const u16* __restrict__ wk_t,
                                                     const u16* __restrict__ wv_t,
                                                     const float* __restrict__ bq,
                                                     const float* __restrict__ bk,
                                                     const float* __restrict__ bv,
                                                     u16* __restrict__ o_ws) {
    __shared__ u16 wS[3 * 32 * 128];   // 24576B: [m][c][k] linear, source-XOR by (c&7)
    __shared__ u16 qS[256 * 32];       // 16384B: [j][c], 16B-chunk XOR-swizzled by (j&3)
    __shared__ u16 kS[256 * 40];       // 20480B: [j][c] pitch 40 (conflict-free reads)
    __shared__ u16 vTS[32 * 264];      // 16896B: [c][j] pitch 264

    // XCD swizzle: the 16 h-blocks of one i stay on one XCD (pair rows L2-shared).
    const int bx = ((blockIdx.x & 7) << 9) | (blockIdx.x >> 3);
    const int i = bx >> 4, h = bx & 15;
    const int tid = threadIdx.x;
    const int wave = tid >> 6, lane = tid & 63;   // wave 0..7
    const int g = lane >> 4, l15 = lane & 15;
    const int j0 = wave * 32;

    // ---- stage W slices: 3 x 8KiB = 24 chunks, 3 per wave (async to LDS) ----
    for (int it = 0; it < 3; ++it) {
        const int chunk = wave * 3 + it;          // 0..23
        const int m = chunk >> 3;
        const int lc = chunk & 7;
        const u16* Wt = (m == 0) ? wq_t : ((m == 1) ? wk_t : wv_t);
        const int c = lc * 4 + (lane >> 4);       // 0..31 within slice
        const int col = (lane & 15) ^ (c & 7);
        gll16((const char*)(Wt + (size_t)(h * 32) * 128) + c * 256 + col * 16,
              (void*)(wS + (m * 32 + lc * 4) * 128));
    }
    // ---- pair rows straight to registers (wave-private!) ----
    s16x8 pf[2][4];
    {
        const u16* prow = pairb + (size_t)(i * 256 + j0 + l15) * 128;
        #pragma unroll
        for (int jf = 0; jf < 2; ++jf)
            #pragma unroll
            for (int kk = 0; kk < 4; ++kk)
                pf[jf][kk] = *reinterpret_cast<const s16x8*>(prow + jf * 16 * 128 + kk * 32 + g * 8);
    }
    __syncthreads();   // drains gll16 (vmcnt) + barrier

    // ---- QKV mini-GEMM: wave owns 32 j-rows x all 32 cols, K=128 ----
    {
        f32x4 aq[2][2], ak[2][2], av[2][2];   // q/k: [cf][jf] (swapped); v: [jf][cf]
        #pragma unroll
        for (int a = 0; a < 2; ++a)
            #pragma unroll
            for (int b = 0; b < 2; ++b) {
                aq[a][b] = f32x4{0.f, 0.f, 0.f, 0.f};
                ak[a][b] = f32x4{0.f, 0.f, 0.f, 0.f};
                av[a][b] = f32x4{0.f, 0.f, 0.f, 0.f};
            }
        #pragma unroll
        for (int kk = 0; kk < 4; ++kk) {
            s16x8 wf[3][2];
            #pragma unroll
            for (int m = 0; m < 3; ++m)
                #pragma unroll
                for (int cf = 0; cf < 2; ++cf) {
                    const int c = cf * 16 + l15;
                    const int ch = (kk * 4 + g) ^ (c & 7);
                    wf[m][cf] = *reinterpret_cast<s16x8*>(&wS[(m * 32 + c) * 128 + ch * 8]);
                }
            #pragma unroll
            for (int cf = 0; cf < 2; ++cf)
                #pragma unroll
                for (int jf = 0; jf < 2; ++jf) {
                    aq[cf][jf] = __builtin_amdgcn_mfma_f32_16x16x32_bf16(wf[0][cf], pf[jf][kk], aq[cf][jf], 0, 0, 0);
                    ak[cf][jf] = __builtin_amdgcn_mfma_f32_16x16x32_bf16(wf[1][cf], pf[jf][kk], ak[cf][jf], 0, 0, 0);
                    av[jf][cf] = __builtin_amdgcn_mfma_f32_16x16x32_bf16(pf[jf][kk], wf[2][cf], av[jf][cf], 0, 0, 0);
                }
        }
        // epilogue: q/k lane holds [j=j0+jf*16+l15][c=cf*16+g*4+(0..3)]
        #pragma unroll
        for (int cf = 0; cf < 2; ++cf) {
            const int c = cf * 16 + g * 4;
            const float4 b4q = *reinterpret_cast<const float4*>(bq + h * 32 + c);
            const float4 b4k = *reinterpret_cast<const float4*>(bk + h * 32 + c);
            #pragma unroll
            for (int jf = 0; jf < 2; ++jf) {
                const int j = j0 + jf * 16 + l15;
                ushort4 oq, ok;
                oq.x = f32_to_bf16((aq[cf][jf][0] + b4q.x) * QSCALE);
                oq.y = f32_to_bf16((aq[cf][jf][1] + b4q.y) * QSCALE);
                oq.z = f32_to_bf16((aq[cf][jf][2] + b4q.z) * QSCALE);
                oq.w = f32_to_bf16((aq[cf][jf][3] + b4q.w) * QSCALE);
                // 16B-chunk XOR swizzle: chunk cc = 2cf + (g>>1), pos = cc ^ (j&3)
                *reinterpret_cast<ushort4*>(
                    &qS[j * 32 + (((cf << 1) + (g >> 1)) ^ (j & 3)) * 8 + (g & 1) * 4]) = oq;
                ok.x = f32_to_bf16(ak[cf][jf][0] + b4k.x);
                ok.y = f32_to_bf16(ak[cf][jf][1] + b4k.y);
                ok.z = f32_to_bf16(ak[cf][jf][2] + b4k.z);
                ok.w = f32_to_bf16(ak[cf][jf][3] + b4k.w);
                *reinterpret_cast<ushort4*>(&kS[j * 40 + c]) = ok;
            }
        }
        // v: lane holds [j=j0+jf*16+g*4+(0..3)][c=cf*16+l15] -> vTS[c][j]
        #pragma unroll
        for (int cf = 0; cf < 2; ++cf) {
            const int c = cf * 16 + l15;
            const float bvv = bv[h * 32 + c];
            #pragma unroll
            for (int jf = 0; jf < 2; ++jf) {
                const int j = j0 + jf * 16 + g * 4;
                ushort4 ov;
                ov.x = f32_to_bf16(av[jf][cf][0] + bvv);
                ov.y = f32_to_bf16(av[jf][cf][1] + bvv);
                ov.z = f32_to_bf16(av[jf][cf][2] + bvv);
                ov.w = f32_to_bf16(av[jf][cf][3] + bvv);
                *reinterpret_cast<ushort4*>(&vTS[c * 264 + j]) = ov;
            }
        }
    }
    __syncthreads();

    // ---- attention: chunks tA=wave, tB=15-wave interleaved (tA < tB always) ----
    const size_t obase = ((size_t)i * 256) * 512 + h * 32;
    const int tA = wave, tB = 15 - wave;

    const s16x8 qfA = *reinterpret_cast<const s16x8*>(
        &qS[(tA * 16 + l15) * 32 + (g ^ (l15 & 3)) * 8]);
    const s16x8 qfB = *reinterpret_cast<const s16x8*>(
        &qS[(tB * 16 + l15) * 32 + (g ^ (l15 & 3)) * 8]);

    f32x4 accA0 = {0.f, 0.f, 0.f, 0.f}, accA1 = {0.f, 0.f, 0.f, 0.f};
    f32x4 accB0 = {0.f, 0.f, 0.f, 0.f}, accB1 = {0.f, 0.f, 0.f, 0.f};
    float sumA = 0.f, sumB = 0.f;

    auto rdK = [&](int kt) {
        return *reinterpret_cast<s16x8*>(&kS[(kt * 16 + l15) * 40 + g * 8]);
    };
    auto rdV0 = [&](int kt) {
        return *reinterpret_cast<s16x4*>(&vTS[l15 * 264 + kt * 16 + g * 4]);
    };
    auto rdV1 = [&](int kt) {
        return *reinterpret_cast<s16x4*>(&vTS[(16 + l15) * 264 + kt * 16 + g * 4]);
    };
    auto tile = [&](const s16x8& kf, const s16x4& va0, const s16x4& va1,
                    const s16x8& qf, f32x4& a0, f32x4& a1, float& sm, bool dg) {
        f32x4 s = __builtin_amdgcn_mfma_f32_16x16x32_bf16(kf, qf, f32x4{0.f, 0.f, 0.f, 0.f}, 0, 0, 0);
        // s[r] = S[k = kt*16 + g*4 + r][j] (log2 domain)
        float p0, p1, p2, p3;
        if (dg) {  // diagonal tile: mask k > j
            p0 = ((g * 4 + 0) > l15) ? 0.f : fast_exp2(s[0]);
            p1 = ((g * 4 + 1) > l15) ? 0.f : fast_exp2(s[1]);
            p2 = ((g * 4 + 2) > l15) ? 0.f : fast_exp2(s[2]);
            p3 = ((g * 4 + 3) > l15) ? 0.f : fast_exp2(s[3]);
        } else {
            p0 = fast_exp2(s[0]); p1 = fast_exp2(s[1]);
            p2 = fast_exp2(s[2]); p3 = fast_exp2(s[3]);
        }
        sm += (p0 + p1) + (p2 + p3);
        unsigned e0 = __builtin_bit_cast(unsigned, p0) + 0x8000u;
        unsigned e1 = __builtin_bit_cast(unsigned, p1) + 0x8000u;
        unsigned e2 = __builtin_bit_cast(unsigned, p2) + 0x8000u;
        unsigned e3 = __builtin_bit_cast(unsigned, p3) + 0x8000u;
        uint2 pw;
        pw.x = __builtin_amdgcn_perm(e1, e0, 0x07060302u);
        pw.y = __builtin_amdgcn_perm(e3, e2, 0x07060302u);
        const s16x4 pb = __builtin_bit_cast(s16x4, pw);
        a0 = mfma_16x16x16_bf16(va0, pb, a0);
        a1 = mfma_16x16x16_bf16(va1, pb, a1);
    };

    for (int kt = 0; kt < tA; ++kt) {
        const s16x8 kf = rdK(kt);
        const s16x4 v0 = rdV0(kt), v1 = rdV1(kt);
        tile(kf, v0, v1, qfB, accB0, accB1, sumB, false);
        tile(kf, v0, v1, qfA, accA0, accA1, sumA, false);
    }
    {   // kt == tA: A's diagonal; B regular (tA < tB)
        const s16x8 kf = rdK(tA);
        const s16x4 v0 = rdV0(tA), v1 = rdV1(tA);
        tile(kf, v0, v1, qfB, accB0, accB1, sumB, false);
        tile(kf, v0, v1, qfA, accA0, accA1, sumA, true);
    }
    for (int kt = tA + 1; kt < tB; ++kt) {
        const s16x8 kf = rdK(kt);
        const s16x4 v0 = rdV0(kt), v1 = rdV1(kt);
        tile(kf, v0, v1, qfB, accB0, accB1, sumB, false);
    }
    {   // kt == tB: B's diagonal
        const s16x8 kf = rdK(tB);
        const s16x4 v0 = rdV0(tB), v1 = rdV1(tB);
        tile(kf, v0, v1, qfB, accB0, accB1, sumB, true);
    }

    auto store_o = [&](int jbase, const f32x4& o0, const f32x4& o1, float sum) {
        sum += __shfl_xor(sum, 16, 64);
        sum += __shfl_xor(sum, 32, 64);
        const float rinv = 1.0f / sum;
        unsigned x0 = __builtin_bit_cast(unsigned, o0[0] * rinv) + 0x8000u;
        unsigned x1 = __builtin_bit_cast(unsigned, o0[1] * rinv) + 0x8000u;
        unsigned x2 = __builtin_bit_cast(unsigned, o0[2] * rinv) + 0x8000u;
        unsigned x3 = __builtin_bit_cast(unsigned, o0[3] * rinv) + 0x8000u;
        uint2 w0;
        w0.x = __builtin_amdgcn_perm(x1, x0, 0x07060302u);
        w0.y = __builtin_amdgcn_perm(x3, x2, 0x07060302u);
        unsigned y0 = __builtin_bit_cast(unsigned, o1[0] * rinv) + 0x8000u;
        unsigned y1 = __builtin_bit_cast(unsigned, o1[1] * rinv) + 0x8000u;
        unsigned y2 = __builtin_bit_cast(unsigned, o1[2] * rinv) + 0x8000u;
        unsigned y3 = __builtin_bit_cast(unsigned, o1[3] * rinv) + 0x8000u;
        uint2 w1;
        w1.x = __builtin_amdgcn_perm(y1, y0, 0x07060302u);
        w1.y = __builtin_amdgcn_perm(y3, y2, 0x07060302u);
        u16* orow = o_ws + obase + (size_t)(jbase + l15) * 512;
        *reinterpret_cast<uint2*>(orow + g * 4) = w0;
        *reinterpret_cast<uint2*>(orow + 16 + g * 4) = w1;
    };
    store_o(tA * 16, accA0, accA1, sumA);
    store_o(tB * 16, accB0, accB1, sumB);
}

// ---------------- output projection + residual ----------------
__global__ __launch_bounds__(256) void outproj(const u16* __restrict__ o_ws,
                                               const u16* __restrict__ wo_t,
                                               const float* __restrict__ pair,
                                               const float* __restrict__ bo,
                                               float* __restrict__ out) {
    __shared__ u16 As[64 * 72];
    __shared__ u16 Bs[128 * 72];
    const int tid = threadIdx.x;
    const int m0 = blockIdx.x * 64;
    const int wave = tid >> 6, lane = tid & 63;
    const int g = lane >> 4, l15 = lane & 15;

    f32x4 acc[8];
    for (int c = 0; c < 8; ++c) acc[c] = f32x4{0.f, 0.f, 0.f, 0.f};

    for (int kt = 0; kt < 8; ++kt) {
        __syncthreads();
        for (int it = 0; it < 2; ++it) {
            int L = tid + it * 256;
            int row = L >> 3, seg = L & 7;
            *reinterpret_cast<s16x8*>(&As[row * 72 + seg * 8]) =
                *reinterpret_cast<const s16x8*>(o_ws + (size_t)(m0 + row) * 512 + kt * 64 + seg * 8);
        }
        for (int it = 0; it < 4; ++it) {
            int L = tid + it * 256;
            int n = L >> 3, seg = L & 7;
            *reinterpret_cast<s16x8*>(&Bs[n * 72 + seg * 8]) =
                *reinterpret_cast<const s16x8*>(wo_t + (size_t)n * 512 + kt * 64 + seg * 8);
        }
        __syncthreads();
        for (int kk = 0; kk < 2; ++kk) {
            const s16x8 a = *reinterpret_cast<s16x8*>(&As[(wave * 16 + l15) * 72 + kk * 32 + g * 8]);
            for (int c = 0; c < 8; ++c) {
                const s16x8 b = *reinterpret_cast<s16x8*>(&Bs[(c * 16 + l15) * 72 + kk * 32 + g * 8]);
                acc[c] = __builtin_amdgcn_mfma_f32_16x16x32_bf16(a, b, acc[c], 0, 0, 0);
            }
        }
    }

    for (int c = 0; c < 8; ++c) {
        const int n = c * 16 + l15;
        const float bias = bo[n];
        for (int r = 0; r < 4; ++r) {
            const size_t row = m0 + wave * 16 + g * 4 + r;
            out[row * 128 + n] = acc[c][r] + bias + pair[row * 128 + n];
        }
    }
}

extern "C" void kernel_launch(void* const* d_in, const int* in_sizes, int n_in,
                              void* d_out, int out_size, void* d_ws, size_t ws_size,
                              hipStream_t stream) {
    const float* pair = (const float*)d_in[0];
    const float* Wq = (const float*)d_in[1];
    const float* bq = (const float*)d_in[2];
    const float* Wk = (const float*)d_in[3];
    const float* bk = (const float*)d_in[4];
    const float* Wv = (const float*)d_in[5];
    const float* bv = (const float*)d_in[6];
    const float* Wo = (const float*)d_in[7];
    const float* bo = (const float*)d_in[8];
    float* out = (float*)d_out;

    char* ws = (char*)d_ws;
    u16* o_ws  = (u16*)(ws);                       // 64 MiB
    u16* wq_t  = (u16*)(ws + 67108864);            // 128 KiB each
    u16* wk_t  = wq_t + 65536;
    u16* wv_t  = wk_t + 65536;
    u16* wo_t  = wv_t + 65536;
    u16* pairb = (u16*)(ws + 67108864 + 1048576);  // 16 MiB

    prep_all<<<5120, 256, 0, stream>>>(Wq, Wk, Wv, Wo, pair,
                                       wq_t, wk_t, wv_t, wo_t, pairb);
    fused_attn<<<4096, 512, 0, stream>>>(pairb, wq_t, wk_t, wv_t, bq, bk, bv, o_ws);
    outproj<<<1024, 256, 0, stream>>>(o_ws, wo_t, pair, bo, out);
}